// Round 3
// baseline (496.492 us; speedup 1.0000x reference)
//
#include <hip/hip_runtime.h>
#include <math.h>

// Problem constants
// x: (B=2, C=32, D=96, H=96, W=96) fp32
// out: (2, 32, 48, 48, 48) fp32
#define HS 0.35355339059327373f   /* 1/(2*sqrt(2)) — 3-stage Haar scale */
#define NSPAT 110592              /* 48^3 */
#define NBN   221184              /* B * 48^3 */

// ---------------------------------------------------------------------------
// K1: per-(b,c) parity sums S[b][c][p][q][r] = sum over x[2i+p][2j+q][2l+r]
// One block per (b,c,d)-plane: 96*96 floats = 2304 float4s, 256 thr * 9.
// (unchanged — streams x once at HBM floor)
// ---------------------------------------------------------------------------
__global__ __launch_bounds__(256) void k1_parity(const float* __restrict__ x,
                                                 float* __restrict__ S) {
    int blk = blockIdx.x;            // (b*32+c)*96 + d
    int d   = blk % 96;
    int bc  = blk / 96;
    const float4* x4 = (const float4*)x + (long)blk * 2304;
    int tid = threadIdx.x;
    float aE0 = 0.f, aO0 = 0.f, aE1 = 0.f, aO1 = 0.f;  // [q][r]
#pragma unroll
    for (int i = 0; i < 9; ++i) {
        int f = tid + i * 256;           // < 2304
        float4 v = x4[f];
        int h = f / 24;                  // row within plane (const-div -> magic mul)
        float e = v.x + v.z, o = v.y + v.w;
        if (h & 1) { aE1 += e; aO1 += o; }
        else       { aE0 += e; aO0 += o; }
    }
#pragma unroll
    for (int m = 32; m; m >>= 1) {
        aE0 += __shfl_xor(aE0, m, 64); aO0 += __shfl_xor(aO0, m, 64);
        aE1 += __shfl_xor(aE1, m, 64); aO1 += __shfl_xor(aO1, m, 64);
    }
    __shared__ float red[4][4];
    int lane = tid & 63, wave = tid >> 6;
    if (lane == 0) { red[wave][0] = aE0; red[wave][1] = aO0;
                     red[wave][2] = aE1; red[wave][3] = aO1; }
    __syncthreads();
    if (tid < 4) {
        float v = red[0][tid] + red[1][tid] + red[2][tid] + red[3][tid];
        int q = tid >> 1, r = tid & 1, p = d & 1;
        atomicAdd(&S[bc * 8 + p * 4 + q * 2 + r], v);
    }
}

// ---------------------------------------------------------------------------
// K2: band means -> two attention MLPs -> effective fuse matrix.
// 16 blocks (b x 8 slices); MLP recomputed redundantly per block (tiny);
// all dots lane-parallel + shfl tree reduce; A-write sliced 8-way.
// A layout: A[b][c][o][pqr] — per-c contiguous 1 KB so K3's block-uniform
// scalar reads batch into wide s_loads.
// ---------------------------------------------------------------------------
__global__ __launch_bounds__(256) void k2_attn(
        const float* __restrict__ S,
        const float* __restrict__ w1l, const float* __restrict__ w2l,
        const float* __restrict__ w1h, const float* __restrict__ w2h,
        const float* __restrict__ wf, float* __restrict__ A) {
    int b = blockIdx.x >> 3, slice = blockIdx.x & 7;
    int tid = threadIdx.x;
    __shared__ float mlow[32], mhigh[224], h1l[2], h1h[14], ylow[32], yhigh[224];
    const float* Sb = S + b * 256;
    const float MS = HS / (float)NSPAT;   // subband mean scale

    // subband means: 256 lanes, one (c, band) each. k=0 -> low, k>=1 -> detail k-1
    {
        int c = tid >> 3, k = tid & 7;
        float s = 0.f;
        if (k == 0) {
#pragma unroll
            for (int j = 0; j < 8; ++j) s += Sb[c * 8 + j];
            mlow[c] = s * MS;
        } else {
#pragma unroll
            for (int j = 0; j < 8; ++j) {
                float sg = (__popc(j & k) & 1) ? -1.f : 1.f;
                s += sg * Sb[c * 8 + j];
            }
            mhigh[c * 7 + (k - 1)] = s * MS;
        }
    }
    __syncthreads();
    // hidden layers: lane-parallel dots + 16-lane shfl tree reduce
    if (tid < 224) {            // h1h[g] = relu(w1h[g,:224] . mhigh)
        int g = tid >> 4, l = tid & 15;
        float p = 0.f;
#pragma unroll
        for (int i = 0; i < 14; ++i)
            p += w1h[g * 224 + l * 14 + i] * mhigh[l * 14 + i];
#pragma unroll
        for (int m = 8; m; m >>= 1) p += __shfl_xor(p, m, 64);
        if (l == 0) h1h[g] = fmaxf(p, 0.f);
    } else {                    // tid in [224,256): h1l[j] = relu(w1l[j,:32] . mlow)
        int j = (tid - 224) >> 4, l = tid & 15;
        float p = w1l[j * 32 + l] * mlow[l] + w1l[j * 32 + 16 + l] * mlow[16 + l];
#pragma unroll
        for (int m = 8; m; m >>= 1) p += __shfl_xor(p, m, 64);
        if (l == 0) h1l[j] = fmaxf(p, 0.f);
    }
    __syncthreads();
    if (tid < 32) {
        float s = w2l[tid * 2] * h1l[0] + w2l[tid * 2 + 1] * h1l[1];
        ylow[tid] = 1.f / (1.f + expf(-s));
    } else {
        int i = tid - 32;       // < 224
        float s = 0.f;
#pragma unroll
        for (int j = 0; j < 14; ++j) s += w2h[i * 14 + j] * h1h[j];
        yhigh[i] = 1.f / (1.f + expf(-s));
    }
    __syncthreads();
    // A-write, sliced 8-way across blocks; layout [b][c][o][pqr]
#pragma unroll
    for (int it = 0; it < 4; ++it) {
        int idx = slice * 1024 + it * 256 + tid;       // < 8192
        int o = idx >> 8, c = (idx >> 3) & 31, pqr = idx & 7;
        float a = wf[o * 256 + c] * ylow[c];
#pragma unroll
        for (int k = 0; k < 7; ++k) {
            float sg = (__popc(pqr & (k + 1)) & 1) ? -1.f : 1.f;
            a += sg * wf[o * 256 + 32 + c * 7 + k] * yhigh[c * 7 + k];
        }
        A[b * 8192 + c * 256 + o * 8 + pqr] = a * HS;
    }
}

// ---------------------------------------------------------------------------
// K3 (main): z[b,o,od,oh,ow] = sum_{c,pqr} A[b,o,c,pqr] * x[b,c,2od+p,2oh+q,2ow+r]
// R6 = R5 with the macro token-pasting compile fix ((s##0).x form).
// R5: og halves MERGED — one block computes ALL 32 output channels.
//  - x streamed ONCE by K3 (was twice): 453 -> 226 MB HBM.
//  - per c-iteration: 4 float4 loads amortized over 1024 FMA-issue cycles
//    -> depth-1 ping-pong covers ~900 cy HBM latency in-wave.
//  - A[b][c][o][pqr]: per-c contiguous 1 KB block-uniform chunk -> s_loads.
// Grid 576 = b(2) x od(48) x ohg(6); block 192 = 8 rows x 24 t.
// ---------------------------------------------------------------------------
#define K3_LOAD(s, cc) { int i4_ = base + (cc) * 221184;                     \
    s##0 = x4[i4_]; s##1 = x4[i4_ + 24];                                     \
    s##2 = x4[i4_ + 2304]; s##3 = x4[i4_ + 2328]; }

#define K3_FMA(s, Aptr) {                                                    \
    _Pragma("unroll")                                                        \
    for (int o = 0; o < 32; ++o) {                                           \
        const float* Ao_ = (Aptr) + o * 8;   /* uniform -> SGPRs */          \
        float a0 = Ao_[0], a1 = Ao_[1], a2 = Ao_[2], a3 = Ao_[3];            \
        float a4 = Ao_[4], a5 = Ao_[5], a6 = Ao_[6], a7 = Ao_[7];            \
        acc0[o] += a0 * (s##0).x + a1 * (s##0).y + a2 * (s##1).x             \
                 + a3 * (s##1).y + a4 * (s##2).x + a5 * (s##2).y             \
                 + a6 * (s##3).x + a7 * (s##3).y;                            \
        acc1[o] += a0 * (s##0).z + a1 * (s##0).w + a2 * (s##1).z             \
                 + a3 * (s##1).w + a4 * (s##2).z + a5 * (s##2).w             \
                 + a6 * (s##3).z + a7 * (s##3).w;                            \
    } }

__global__ __launch_bounds__(192) void k3_main(const float* __restrict__ x,
                                               const float* __restrict__ A,
                                               float* __restrict__ z,
                                               float* __restrict__ bnSum,
                                               float* __restrict__ bnSq) {
    __shared__ float red[3][64];
    int blk = blockIdx.x;              // (b*48+od)*6+ohg
    int ohg = blk % 6;
    int tmp = blk / 6;
    int od  = tmp % 48;
    int b   = tmp / 48;
    int tid = threadIdx.x;
    int row = tid / 24;                // 0..7
    int t   = tid % 24;                // ow-pair: outputs 2t, 2t+1
    int oh  = ohg * 8 + row;

    const float* Ab = A + b * 8192;    // [c<32][o<32][pqr<8], block-uniform

    float acc0[32], acc1[32];
#pragma unroll
    for (int o = 0; o < 32; ++o) { acc0[o] = 0.f; acc1[o] = 0.f; }

    const float4* x4 = (const float4*)x;
    // float4 index for (b, c, 2od+p, 2oh+q, 4t): channel stride 96^3/4 = 221184
    int base = (((b * 32) * 96 + 2 * od) * 96 + 2 * oh) * 24 + t;

    float4 pa0, pa1, pa2, pa3, pb0, pb1, pb2, pb3;
    K3_LOAD(pa, 0);
    for (int c = 0; c < 32; c += 2) {
        K3_LOAD(pb, c + 1);
        const float* Ac = Ab + c * 256;
        K3_FMA(pa, Ac);
        if (c + 2 < 32) K3_LOAD(pa, c + 2);
        K3_FMA(pb, Ac + 256);
    }

    // write z (staged in d_out), coalesced float2 per o
    float2* z2 = (float2*)z;
#pragma unroll
    for (int o = 0; o < 32; ++o) {
        int zi = (((b * 32 + o) * 48 + od) * 48 + oh) * 24 + t;
        z2[zi] = make_float2(acc0[o], acc1[o]);
    }

    // BN partial sums for all 32 channels
    int lane = tid & 63, wave = tid >> 6;
#pragma unroll
    for (int o = 0; o < 32; ++o) {
        float sv = acc0[o] + acc1[o];
        float qv = acc0[o] * acc0[o] + acc1[o] * acc1[o];
#pragma unroll
        for (int m = 32; m; m >>= 1) {
            sv += __shfl_xor(sv, m, 64);
            qv += __shfl_xor(qv, m, 64);
        }
        if (lane == 0) { red[wave][o] = sv; red[wave][32 + o] = qv; }
    }
    __syncthreads();
    if (tid < 64) {
        float v = red[0][tid] + red[1][tid] + red[2][tid];
        if (tid < 32) atomicAdd(&bnSum[tid], v);
        else          atomicAdd(&bnSq[tid - 32], v);
    }
}

// ---------------------------------------------------------------------------
// K5: BN finalize (per-block recompute) + normalize + ReLU, in place over
// z (= d_out). 1769472 float4s exactly. b_fuse cancels under BN mean-subtract.
// ---------------------------------------------------------------------------
__global__ __launch_bounds__(256) void k5_norm(float* __restrict__ z,
                                               const float* __restrict__ bnSum,
                                               const float* __restrict__ bnSq,
                                               const float* __restrict__ gamma,
                                               const float* __restrict__ beta) {
    __shared__ float s_sc[32], s_sh[32];
    int tid = threadIdx.x;
    if (tid < 32) {
        const float invN = 1.f / (float)NBN;
        float mean = bnSum[tid] * invN;
        float var  = bnSq[tid] * invN - mean * mean;
        float inv  = rsqrtf(var + 1e-5f);
        float sc   = gamma[tid] * inv;
        s_sc[tid] = sc;
        s_sh[tid] = beta[tid] - mean * sc;
    }
    int i = blockIdx.x * 256 + tid;                // float4 index
    float4* z4 = (float4*)z;
    float4 v = z4[i];                              // load before barrier (indep)
    __syncthreads();
    int o = (i / 27648) & 31;                      // 27648 = 48^3/4
    float sc = s_sc[o], sh = s_sh[o];
    v.x = fmaxf(v.x * sc + sh, 0.f);
    v.y = fmaxf(v.y * sc + sh, 0.f);
    v.z = fmaxf(v.z * sc + sh, 0.f);
    v.w = fmaxf(v.w * sc + sh, 0.f);
    z4[i] = v;
}

extern "C" void kernel_launch(void* const* d_in, const int* in_sizes, int n_in,
                              void* d_out, int out_size, void* d_ws, size_t ws_size,
                              hipStream_t stream) {
    const float* x    = (const float*)d_in[0];
    const float* w1l  = (const float*)d_in[1];
    const float* w2l  = (const float*)d_in[2];
    const float* w1h  = (const float*)d_in[3];
    const float* w2h  = (const float*)d_in[4];
    const float* wf   = (const float*)d_in[5];
    // d_in[6] = b_fuse: cancels exactly under training-mode BN (mean subtract)
    const float* gamma = (const float*)d_in[7];
    const float* beta  = (const float*)d_in[8];
    float* out = (float*)d_out;

    float* ws    = (float*)d_ws;
    float* S     = ws;          // 512 floats (zeroed)
    float* bnSum = ws + 512;    // 32 (zeroed)
    float* bnSq  = ws + 544;    // 32 (zeroed)
    float* A     = ws + 1024;   // 16384 floats, layout [b][c][o][pqr]

    hipMemsetAsync(d_ws, 0, 576 * sizeof(float), stream);
    k1_parity<<<6144, 256, 0, stream>>>(x, S);
    k2_attn<<<16, 256, 0, stream>>>(S, w1l, w2l, w1h, w2h, wf, A);
    k3_main<<<576, 192, 0, stream>>>(x, A, out, bnSum, bnSq);
    k5_norm<<<6912, 256, 0, stream>>>(out, bnSum, bnSq, gamma, beta);
}

// Round 4
// 439.872 us; speedup vs baseline: 1.1287x; 1.1287x over previous
//
#include <hip/hip_runtime.h>
#include <math.h>

// Problem constants
// x: (B=2, C=32, D=96, H=96, W=96) fp32
// out: (2, 32, 48, 48, 48) fp32
#define HS 0.35355339059327373f   /* 1/(2*sqrt(2)) — 3-stage Haar scale */
#define NSPAT 110592              /* 48^3 */
#define NBN   221184              /* B * 48^3 */

// ---------------------------------------------------------------------------
// K1: per-(b,c) parity sums S[b][c][p][q][r] = sum over x[2i+p][2j+q][2l+r]
// One block per (b,c,d)-plane: 96*96 floats = 2304 float4s, 256 thr * 9.
// (unchanged — streams x once at HBM floor)
// ---------------------------------------------------------------------------
__global__ __launch_bounds__(256) void k1_parity(const float* __restrict__ x,
                                                 float* __restrict__ S) {
    int blk = blockIdx.x;            // (b*32+c)*96 + d
    int d   = blk % 96;
    int bc  = blk / 96;
    const float4* x4 = (const float4*)x + (long)blk * 2304;
    int tid = threadIdx.x;
    float aE0 = 0.f, aO0 = 0.f, aE1 = 0.f, aO1 = 0.f;  // [q][r]
#pragma unroll
    for (int i = 0; i < 9; ++i) {
        int f = tid + i * 256;           // < 2304
        float4 v = x4[f];
        int h = f / 24;                  // row within plane (const-div -> magic mul)
        float e = v.x + v.z, o = v.y + v.w;
        if (h & 1) { aE1 += e; aO1 += o; }
        else       { aE0 += e; aO0 += o; }
    }
#pragma unroll
    for (int m = 32; m; m >>= 1) {
        aE0 += __shfl_xor(aE0, m, 64); aO0 += __shfl_xor(aO0, m, 64);
        aE1 += __shfl_xor(aE1, m, 64); aO1 += __shfl_xor(aO1, m, 64);
    }
    __shared__ float red[4][4];
    int lane = tid & 63, wave = tid >> 6;
    if (lane == 0) { red[wave][0] = aE0; red[wave][1] = aO0;
                     red[wave][2] = aE1; red[wave][3] = aO1; }
    __syncthreads();
    if (tid < 4) {
        float v = red[0][tid] + red[1][tid] + red[2][tid] + red[3][tid];
        int q = tid >> 1, r = tid & 1, p = d & 1;
        atomicAdd(&S[bc * 8 + p * 4 + q * 2 + r], v);
    }
}

// ---------------------------------------------------------------------------
// K2: band means -> two attention MLPs -> effective fuse matrix.
// 16 blocks (b x 8 slices); MLP recomputed redundantly per block (tiny);
// all dots lane-parallel + shfl tree reduce; A-write sliced 8-way.
// A layout: A[b][c][o][pqr] — per-(c,og) contiguous 512 B, so K3 can stage
// its og-slice into LDS with plain float4 loads.
// ---------------------------------------------------------------------------
__global__ __launch_bounds__(256) void k2_attn(
        const float* __restrict__ S,
        const float* __restrict__ w1l, const float* __restrict__ w2l,
        const float* __restrict__ w1h, const float* __restrict__ w2h,
        const float* __restrict__ wf, float* __restrict__ A) {
    int b = blockIdx.x >> 3, slice = blockIdx.x & 7;
    int tid = threadIdx.x;
    __shared__ float mlow[32], mhigh[224], h1l[2], h1h[14], ylow[32], yhigh[224];
    const float* Sb = S + b * 256;
    const float MS = HS / (float)NSPAT;   // subband mean scale

    // subband means: 256 lanes, one (c, band) each. k=0 -> low, k>=1 -> detail k-1
    {
        int c = tid >> 3, k = tid & 7;
        float s = 0.f;
        if (k == 0) {
#pragma unroll
            for (int j = 0; j < 8; ++j) s += Sb[c * 8 + j];
            mlow[c] = s * MS;
        } else {
#pragma unroll
            for (int j = 0; j < 8; ++j) {
                float sg = (__popc(j & k) & 1) ? -1.f : 1.f;
                s += sg * Sb[c * 8 + j];
            }
            mhigh[c * 7 + (k - 1)] = s * MS;
        }
    }
    __syncthreads();
    // hidden layers: lane-parallel dots + 16-lane shfl tree reduce
    if (tid < 224) {            // h1h[g] = relu(w1h[g,:224] . mhigh)
        int g = tid >> 4, l = tid & 15;
        float p = 0.f;
#pragma unroll
        for (int i = 0; i < 14; ++i)
            p += w1h[g * 224 + l * 14 + i] * mhigh[l * 14 + i];
#pragma unroll
        for (int m = 8; m; m >>= 1) p += __shfl_xor(p, m, 64);
        if (l == 0) h1h[g] = fmaxf(p, 0.f);
    } else {                    // tid in [224,256): h1l[j] = relu(w1l[j,:32] . mlow)
        int j = (tid - 224) >> 4, l = tid & 15;
        float p = w1l[j * 32 + l] * mlow[l] + w1l[j * 32 + 16 + l] * mlow[16 + l];
#pragma unroll
        for (int m = 8; m; m >>= 1) p += __shfl_xor(p, m, 64);
        if (l == 0) h1l[j] = fmaxf(p, 0.f);
    }
    __syncthreads();
    if (tid < 32) {
        float s = w2l[tid * 2] * h1l[0] + w2l[tid * 2 + 1] * h1l[1];
        ylow[tid] = 1.f / (1.f + expf(-s));
    } else {
        int i = tid - 32;       // < 224
        float s = 0.f;
#pragma unroll
        for (int j = 0; j < 14; ++j) s += w2h[i * 14 + j] * h1h[j];
        yhigh[i] = 1.f / (1.f + expf(-s));
    }
    __syncthreads();
    // A-write, sliced 8-way across blocks; layout [b][c][o][pqr]
#pragma unroll
    for (int it = 0; it < 4; ++it) {
        int idx = slice * 1024 + it * 256 + tid;       // < 8192
        int o = idx >> 8, c = (idx >> 3) & 31, pqr = idx & 7;
        float a = wf[o * 256 + c] * ylow[c];
#pragma unroll
        for (int k = 0; k < 7; ++k) {
            float sg = (__popc(pqr & (k + 1)) & 1) ? -1.f : 1.f;
            a += sg * wf[o * 256 + 32 + c * 7 + k] * yhigh[c * 7 + k];
        }
        A[b * 8192 + c * 256 + o * 8 + pqr] = a * HS;
    }
}

// ---------------------------------------------------------------------------
// K3 (main): z[b,o,od,oh,ow] = sum_{c,pqr} A[b,o,c,pqr] * x[b,c,2od+p,2oh+q,2ow+r]
// R7 post-mortem of the og-merge (R6 counters): VGPR capped at 64 -> 64 accs
// spilled through AGPRs (VALU inflated), occupancy 18% (1.7 waves/SIMD) ->
// latency exposed; FETCH showed x is L3-resident after K1, so the double
// x-read og-split avoids was never a real cost. Revert to og-split and fix
// the latency path:
//  - 16 o per block, grid 1152 (4.5 blk/CU, 13.5 waves/CU ~ 42% occupancy);
//    32 accs + 16 prefetch floats ~ 80-96 VGPR, no spills.
//  - A og-slice (32c x 16o x 8 = 16 KB) staged in LDS ONCE per block;
//    inner loop reads A by uniform ds_read broadcast (conflict-free),
//    removing the SGPR-windowed s_load dependency chains.
//  - XCD-twin swizzle kept: og twins (same x-slab) land on same XCD L2.
// Block 192 = 8 rows x 24 t; depth-1 ping-pong x prefetch.
// ---------------------------------------------------------------------------
#define K3_LOAD(s, cc) { int i4_ = base + (cc) * 221184;                     \
    s##0 = x4[i4_]; s##1 = x4[i4_ + 24];                                     \
    s##2 = x4[i4_ + 2304]; s##3 = x4[i4_ + 2328]; }

#define K3_FMA(s, Aptr) {                                                    \
    _Pragma("unroll")                                                        \
    for (int o = 0; o < 16; ++o) {                                           \
        const float* Ao_ = (Aptr) + o * 8;   /* uniform LDS broadcast */     \
        float a0 = Ao_[0], a1 = Ao_[1], a2 = Ao_[2], a3 = Ao_[3];            \
        float a4 = Ao_[4], a5 = Ao_[5], a6 = Ao_[6], a7 = Ao_[7];            \
        acc0[o] += a0 * (s##0).x + a1 * (s##0).y + a2 * (s##1).x             \
                 + a3 * (s##1).y + a4 * (s##2).x + a5 * (s##2).y             \
                 + a6 * (s##3).x + a7 * (s##3).y;                            \
        acc1[o] += a0 * (s##0).z + a1 * (s##0).w + a2 * (s##1).z             \
                 + a3 * (s##1).w + a4 * (s##2).z + a5 * (s##2).w             \
                 + a6 * (s##3).z + a7 * (s##3).w;                            \
    } }

__global__ __launch_bounds__(192) void k3_main(const float* __restrict__ x,
                                               const float* __restrict__ A,
                                               float* __restrict__ z,
                                               float* __restrict__ bnSum,
                                               float* __restrict__ bnSq) {
    __shared__ float sA[4096];         // og-slice: [c<32][o'<16][pqr<8]
    __shared__ float red[3][32];
    int blk  = blockIdx.x;             // [resthi(7b) | og(1b) | restlo(3b)]
    int og   = (blk >> 3) & 1;
    int rest = (blk & 7) | ((blk >> 4) << 3);   // 0..575
    int ohg  = rest % 6;
    int tmp  = rest / 6;
    int od   = tmp % 48;
    int b    = tmp / 48;
    int tid = threadIdx.x;
    int row = tid / 24;                // 0..7
    int t   = tid % 24;                // ow-pair: outputs 2t, 2t+1
    int oh  = ohg * 8 + row;

    const float4* x4 = (const float4*)x;
    // float4 index for (b, c, 2od+p, 2oh+q, 4t): channel stride 96^3/4 = 221184
    int base = (((b * 32) * 96 + 2 * od) * 96 + 2 * oh) * 24 + t;

    // stage A og-slice into LDS: sA[c*128 + o'*8 + pqr] = A[b][c][og*16+o'][pqr]
    {
        const float4* A4 = (const float4*)A;
        int srcbase = b * 2048 + og * 32;     // float4 units
        float4* sA4 = (float4*)sA;
        for (int s = tid; s < 1024; s += 192) {
            int c = s >> 5, j = s & 31;
            sA4[s] = A4[srcbase + c * 64 + j];
        }
    }

    float acc0[16], acc1[16];
#pragma unroll
    for (int o = 0; o < 16; ++o) { acc0[o] = 0.f; acc1[o] = 0.f; }

    float4 pa0, pa1, pa2, pa3, pb0, pb1, pb2, pb3;
    K3_LOAD(pa, 0);                    // x prefetch overlaps A staging
    __syncthreads();

    for (int c = 0; c < 32; c += 2) {
        K3_LOAD(pb, c + 1);
        const float* Ac = sA + c * 128;
        K3_FMA(pa, Ac);
        if (c + 2 < 32) K3_LOAD(pa, c + 2);
        K3_FMA(pb, Ac + 128);
    }

    // write z (staged in d_out), coalesced float2 per o
    float2* z2 = (float2*)z;
#pragma unroll
    for (int o = 0; o < 16; ++o) {
        int zi = (((b * 32 + og * 16 + o) * 48 + od) * 48 + oh) * 24 + t;
        z2[zi] = make_float2(acc0[o], acc1[o]);
    }

    // BN partial sums for this block's 16 channels
    int lane = tid & 63, wave = tid >> 6;
#pragma unroll
    for (int o = 0; o < 16; ++o) {
        float sv = acc0[o] + acc1[o];
        float qv = acc0[o] * acc0[o] + acc1[o] * acc1[o];
#pragma unroll
        for (int m = 32; m; m >>= 1) {
            sv += __shfl_xor(sv, m, 64);
            qv += __shfl_xor(qv, m, 64);
        }
        if (lane == 0) { red[wave][o] = sv; red[wave][16 + o] = qv; }
    }
    __syncthreads();
    if (tid < 32) {
        float v = red[0][tid] + red[1][tid] + red[2][tid];
        if (tid < 16) atomicAdd(&bnSum[og * 16 + tid], v);
        else          atomicAdd(&bnSq[og * 16 + tid - 16], v);
    }
}

// ---------------------------------------------------------------------------
// K5: BN finalize (per-block recompute) + normalize + ReLU, in place over
// z (= d_out). 1769472 float4s exactly. b_fuse cancels under BN mean-subtract.
// ---------------------------------------------------------------------------
__global__ __launch_bounds__(256) void k5_norm(float* __restrict__ z,
                                               const float* __restrict__ bnSum,
                                               const float* __restrict__ bnSq,
                                               const float* __restrict__ gamma,
                                               const float* __restrict__ beta) {
    __shared__ float s_sc[32], s_sh[32];
    int tid = threadIdx.x;
    if (tid < 32) {
        const float invN = 1.f / (float)NBN;
        float mean = bnSum[tid] * invN;
        float var  = bnSq[tid] * invN - mean * mean;
        float inv  = rsqrtf(var + 1e-5f);
        float sc   = gamma[tid] * inv;
        s_sc[tid] = sc;
        s_sh[tid] = beta[tid] - mean * sc;
    }
    int i = blockIdx.x * 256 + tid;                // float4 index
    float4* z4 = (float4*)z;
    float4 v = z4[i];                              // load before barrier (indep)
    __syncthreads();
    int o = (i / 27648) & 31;                      // 27648 = 48^3/4
    float sc = s_sc[o], sh = s_sh[o];
    v.x = fmaxf(v.x * sc + sh, 0.f);
    v.y = fmaxf(v.y * sc + sh, 0.f);
    v.z = fmaxf(v.z * sc + sh, 0.f);
    v.w = fmaxf(v.w * sc + sh, 0.f);
    z4[i] = v;
}

extern "C" void kernel_launch(void* const* d_in, const int* in_sizes, int n_in,
                              void* d_out, int out_size, void* d_ws, size_t ws_size,
                              hipStream_t stream) {
    const float* x    = (const float*)d_in[0];
    const float* w1l  = (const float*)d_in[1];
    const float* w2l  = (const float*)d_in[2];
    const float* w1h  = (const float*)d_in[3];
    const float* w2h  = (const float*)d_in[4];
    const float* wf   = (const float*)d_in[5];
    // d_in[6] = b_fuse: cancels exactly under training-mode BN (mean subtract)
    const float* gamma = (const float*)d_in[7];
    const float* beta  = (const float*)d_in[8];
    float* out = (float*)d_out;

    float* ws    = (float*)d_ws;
    float* S     = ws;          // 512 floats (zeroed)
    float* bnSum = ws + 512;    // 32 (zeroed)
    float* bnSq  = ws + 544;    // 32 (zeroed)
    float* A     = ws + 1024;   // 16384 floats, layout [b][c][o][pqr]

    hipMemsetAsync(d_ws, 0, 576 * sizeof(float), stream);
    k1_parity<<<6144, 256, 0, stream>>>(x, S);
    k2_attn<<<16, 256, 0, stream>>>(S, w1l, w2l, w1h, w2h, wf, A);
    k3_main<<<1152, 192, 0, stream>>>(x, A, out, bnSum, bnSq);
    k5_norm<<<6912, 256, 0, stream>>>(out, bnSum, bnSq, gamma, beta);
}